// Round 1
// 635.552 us; speedup vs baseline: 1.2844x; 1.2844x over previous
//
#include <hip/hip_runtime.h>
#include <math.h>

#define H      1024
#define NA     512
#define NI     256
#define SEQ    4096
#define BATCH  4
#define NTOK   (BATCH*SEQ)      // 16384
#define MTOK   16               // tokens per block in score kernel
#define KC     8                // K chunk staged in LDS (weights + tokens)
#define PT     20               // padded token stride
#define SINKN  4
#define RECENTN 19
#define MIDN   (SEQ - SINKN - RECENTN)   // 4073
#define KSEL   2025
#define CHK    16               // per-thread contiguous chunk in select kernel

// ---------------------------------------------------------------------------
// Kernel 1: fused two-layer MLP scores for att (keys) and imp (values).
// scores[b*S+s] = 0.6*sigmoid(relu(k@W1a+b1a)@W2a+b2a) + 0.4*(relu(v@W1i+b1i)@W2i+b2i)
// block = 256 threads, 16 tokens/block (1024 blocks -> 4 blocks/CU).
// v2: weights staged in LDS per KC=8 chunk so the 4 waves share ONE L2 fetch
// of each weight row instead of 4 redundant ones (L2 traffic 12.6GB -> 3.2GB).
// FMA order per accumulator is identical to v1 -> scores bit-identical.
// ---------------------------------------------------------------------------
__global__ __launch_bounds__(256, 4) void score_kernel(
    const float* __restrict__ keys, const float* __restrict__ values,
    const float* __restrict__ W1a, const float* __restrict__ b1a,
    const float* __restrict__ W2a, const float* __restrict__ b2a,
    const float* __restrict__ W1i, const float* __restrict__ b1i,
    const float* __restrict__ W2i, const float* __restrict__ b2i,
    float* __restrict__ scores)
{
    // LDS: wa[KC][NA] (16KB) + wi[KC][NI] (8KB) + k/v [KC][PT] (1.25KB) = 25.9KB
    __shared__ __align__(16) float smem[KC * NA + KC * NI + 2 * KC * PT];
    float* wa_lds = smem;                       // [KC][NA]
    float* wi_lds = smem + KC * NA;             // [KC][NI]
    float* k_lds  = smem + KC * (NA + NI);      // [KC][PT]
    float* v_lds  = k_lds + KC * PT;

    const int tid  = threadIdx.x;
    const int to   = tid & 63;
    const int tt   = tid >> 6;
    const int tokb = blockIdx.x * MTOK;

    float accA0[4][4], accA1[4][4], accI[4][4];
#pragma unroll
    for (int j = 0; j < 4; ++j)
#pragma unroll
        for (int t = 0; t < 4; ++t) { accA0[j][t] = 0.f; accA1[j][t] = 0.f; accI[j][t] = 0.f; }

    // token staging role: every 4th thread (16/wave -> spread across waves)
    // loads one float4 of keys or values for this chunk.
    const bool st_on = (tid & 3) == 0;
    const int  item  = tid >> 2;                // 0..63
    const int  st_t  = item & 15;               // token within block
    const int  st_q  = (item >> 4) & 1;         // h-quad within chunk (0..1)
    const bool st_v  = (item >> 5) & 1;         // 0 = keys, 1 = values
    const float* st_src = (st_v ? values : keys) + (size_t)(tokb + st_t) * H + st_q * 4;
    float* st_dst = (st_v ? v_lds : k_lds);

    for (int h0 = 0; h0 < H; h0 += KC) {
        // issue this chunk's global loads early (reg dest), overlap barrier wait
        const float4* wap = (const float4*)(W1a + (size_t)h0 * NA);  // 1024 f4
        const float4* wip = (const float4*)(W1i + (size_t)h0 * NI);  // 512 f4
        float4 wb0 = wap[tid];
        float4 wb1 = wap[tid + 256];
        float4 wb2 = wap[tid + 512];
        float4 wb3 = wap[tid + 768];
        float4 ib0 = wip[tid];
        float4 ib1 = wip[tid + 256];
        float4 tk;
        if (st_on) tk = *(const float4*)(st_src + h0);

        __syncthreads();                        // previous chunk fully consumed
        ((float4*)wa_lds)[tid      ] = wb0;
        ((float4*)wa_lds)[tid + 256] = wb1;
        ((float4*)wa_lds)[tid + 512] = wb2;
        ((float4*)wa_lds)[tid + 768] = wb3;
        ((float4*)wi_lds)[tid      ] = ib0;
        ((float4*)wi_lds)[tid + 256] = ib1;
        if (st_on) {
            st_dst[(st_q * 4 + 0) * PT + st_t] = tk.x;
            st_dst[(st_q * 4 + 1) * PT + st_t] = tk.y;
            st_dst[(st_q * 4 + 2) * PT + st_t] = tk.z;
            st_dst[(st_q * 4 + 3) * PT + st_t] = tk.w;
        }
        __syncthreads();

#pragma unroll
        for (int h = 0; h < KC; ++h) {
            float kf[4], vf[4], wa[8], wi4[4];
            *(float4*)&kf[0]  = *(const float4*)&k_lds[h * PT + tt * 4];   // broadcast
            *(float4*)&vf[0]  = *(const float4*)&v_lds[h * PT + tt * 4];   // broadcast
            *(float4*)&wa[0]  = *(const float4*)&wa_lds[h * NA + to * 4];
            *(float4*)&wa[4]  = *(const float4*)&wa_lds[h * NA + 256 + to * 4];
            *(float4*)&wi4[0] = *(const float4*)&wi_lds[h * NI + to * 4];
#pragma unroll
            for (int j = 0; j < 4; ++j)
#pragma unroll
                for (int t = 0; t < 4; ++t) {
                    accA0[j][t] = fmaf(kf[t], wa[j],     accA0[j][t]);
                    accA1[j][t] = fmaf(kf[t], wa[4 + j], accA1[j][t]);
                    accI[j][t]  = fmaf(vf[t], wi4[j],    accI[j][t]);
                }
        }
    }

    // ---- epilogue: second layers (identical to v1) ----
    float b1aA[8], w2aA[8], b1iA[4], w2iA[4];
    *(float4*)&b1aA[0] = *(const float4*)(b1a + to * 4);
    *(float4*)&b1aA[4] = *(const float4*)(b1a + 256 + to * 4);
    *(float4*)&w2aA[0] = *(const float4*)(W2a + to * 4);
    *(float4*)&w2aA[4] = *(const float4*)(W2a + 256 + to * 4);
    *(float4*)&b1iA[0] = *(const float4*)(b1i + to * 4);
    *(float4*)&w2iA[0] = *(const float4*)(W2i + to * 4);

    __syncthreads();                      // done with staging LDS
    float* red_a = smem;                  // [16][65] padded
    float* red_i = smem + 16 * 65;

#pragma unroll
    for (int t = 0; t < 4; ++t) {
        float pa = 0.f, pi = 0.f;
#pragma unroll
        for (int j = 0; j < 4; ++j) {
            pa += fmaxf(accA0[j][t] + b1aA[j],     0.f) * w2aA[j];
            pa += fmaxf(accA1[j][t] + b1aA[4 + j], 0.f) * w2aA[4 + j];
            pi += fmaxf(accI[j][t]  + b1iA[j],     0.f) * w2iA[j];
        }
        const int tg = tt * 4 + t;
        red_a[tg * 65 + to] = pa;
        red_i[tg * 65 + to] = pi;
    }
    __syncthreads();
    if (tid < MTOK) {
        float sa = 0.f, si = 0.f;
        for (int j2 = 0; j2 < 64; ++j2) {
            sa += red_a[tid * 65 + j2];
            si += red_i[tid * 65 + j2];
        }
        const float att = 1.f / (1.f + expf(-(sa + b2a[0])));
        scores[tokb + tid] = 0.6f * att + 0.4f * (si + b2i[0]);
    }
}

// ---------------------------------------------------------------------------
// block-wide sum (256 threads), result broadcast to all threads
// ---------------------------------------------------------------------------
__device__ __forceinline__ int block_sum(int val, int* red, int tid)
{
#pragma unroll
    for (int off = 32; off > 0; off >>= 1) val += __shfl_down(val, off);
    if ((tid & 63) == 0) red[tid >> 6] = val;
    __syncthreads();
    const int total = red[0] + red[1] + red[2] + red[3];
    __syncthreads();
    return total;
}

// ---------------------------------------------------------------------------
// Kernel 2: per-row exact top-KSEL of the 4073 middle scores -> float mask.
// 4-pass byte-radix select on sign-flipped uint keys; ties kept lowest-index
// first. v2: the serial tid==0 histogram walks and tie scan are replaced by
// 256-thread Hillis-Steele suffix/prefix scans (integer-exact, same result).
// ---------------------------------------------------------------------------
__global__ __launch_bounds__(256) void select_kernel(
    const float* __restrict__ scores, float* __restrict__ mask)
{
    __shared__ unsigned int ks[MIDN];
    __shared__ int hist[256];
    __shared__ int red[4];
    __shared__ int scan_s[256];
    __shared__ unsigned int sh_pref;
    __shared__ int sh_r;

    const int tid = threadIdx.x;
    const int row = blockIdx.x;
    const float* sr = scores + row * SEQ;

    for (int i = tid; i < MIDN; i += 256) {
        unsigned int u = __float_as_uint(sr[SINKN + i]);
        u = (u & 0x80000000u) ? ~u : (u | 0x80000000u);   // order-preserving map
        ks[i] = u;
    }
    if (tid == 0) { sh_pref = 0u; sh_r = KSEL; }
    __syncthreads();

    // byte-radix: after 4 passes sh_pref == KSEL-th largest key value
    for (int b = 3; b >= 0; --b) {
        hist[tid] = 0;
        __syncthreads();
        const unsigned int hi_mask = (b == 3) ? 0u : (0xFFFFFFFFu << ((b + 1) * 8));
        const unsigned int pref = sh_pref;
        for (int i = tid; i < MIDN; i += 256) {
            const unsigned int u = ks[i];
            if ((u & hi_mask) == pref)
                atomicAdd(&hist[(u >> (b * 8)) & 255], 1);
        }
        __syncthreads();

        // inclusive suffix-sum of hist into scan_s (Hillis-Steele, 8 rounds)
        scan_s[tid] = hist[tid];
        __syncthreads();
#pragma unroll
        for (int off = 1; off < 256; off <<= 1) {
            const int add = (tid + off < 256) ? scan_s[tid + off] : 0;
            __syncthreads();
            scan_s[tid] += add;
            __syncthreads();
        }
        const int r    = sh_r;                       // stable: written last pass
        const int sfx  = scan_s[tid];                // suffix(tid)
        const int sfx1 = (tid < 255) ? scan_s[tid + 1] : 0;
        if (sfx >= r && sfx1 < r) {                  // unique winner: largest d with suffix>=r
            sh_r = r - sfx1;
            sh_pref = pref | ((unsigned int)tid << (b * 8));
        }
        __syncthreads();
    }
    const unsigned int v = sh_pref;

    const int st = tid * CHK;
    const int en = (st + CHK < MIDN) ? (st + CHK) : MIDN;

    int cgt = 0, ceq = 0;
    for (int k = st; k < en; ++k) { cgt += (ks[k] > v) ? 1 : 0; ceq += (ks[k] == v) ? 1 : 0; }
    const int total_gt = block_sum(cgt, red, tid);
    const int need = KSEL - total_gt;      // #ties to keep (>=1 by construction)

    // exclusive prefix-sum of tie counts (parallel)
    scan_s[tid] = ceq;
    __syncthreads();
#pragma unroll
    for (int off = 1; off < 256; off <<= 1) {
        const int add = (tid >= off) ? scan_s[tid - off] : 0;
        __syncthreads();
        scan_s[tid] += add;
        __syncthreads();
    }
    int r = scan_s[tid] - ceq;             // exclusive prefix

    float* mr = mask + row * SEQ;
    for (int k = st; k < en; ++k) {
        const unsigned int u = ks[k];
        bool keep = false;
        if (u > v) keep = true;
        else if (u == v) { keep = (r < need); ++r; }
        mr[SINKN + k] = keep ? 1.f : 0.f;
    }
    for (int s = tid; s < SEQ; s += 256) {
        if (s < SINKN || s >= SEQ - RECENTN) mr[s] = 1.f;
    }
}

// ---------------------------------------------------------------------------
// Kernel 3: out = concat(keys*mask, values*mask), float4 grid-stride.
// ---------------------------------------------------------------------------
__global__ __launch_bounds__(256) void apply_kernel(
    const float* __restrict__ keys, const float* __restrict__ values,
    const float* __restrict__ mask, float* __restrict__ out)
{
    const int QT = NTOK * H / 4;          // 4194304 float4 per tensor
    const int stride = gridDim.x * 256;
    for (int i4 = blockIdx.x * 256 + threadIdx.x; i4 < 2 * QT; i4 += stride) {
        const bool isv = (i4 >= QT);
        const int  j4  = isv ? (i4 - QT) : i4;
        const float m  = mask[j4 >> 8];   // 256 float4 per token row
        const float4* src = isv ? (const float4*)values : (const float4*)keys;
        const float4 x = src[j4];
        float4 y; y.x = x.x * m; y.y = x.y * m; y.z = x.z * m; y.w = x.w * m;
        ((float4*)out)[i4] = y;
    }
}

extern "C" void kernel_launch(void* const* d_in, const int* in_sizes, int n_in,
                              void* d_out, int out_size, void* d_ws, size_t ws_size,
                              hipStream_t stream)
{
    const float* keys   = (const float*)d_in[0];
    const float* values = (const float*)d_in[1];
    const float* W1a = (const float*)d_in[2];
    const float* b1a = (const float*)d_in[3];
    const float* W2a = (const float*)d_in[4];
    const float* b2a = (const float*)d_in[5];
    const float* W1i = (const float*)d_in[6];
    const float* b1i = (const float*)d_in[7];
    const float* W2i = (const float*)d_in[8];
    const float* b2i = (const float*)d_in[9];

    float* scores = (float*)d_ws;          // NTOK floats
    float* mask   = scores + NTOK;         // NTOK floats

    score_kernel<<<NTOK / MTOK, 256, 0, stream>>>(keys, values, W1a, b1a, W2a, b2a,
                                                  W1i, b1i, W2i, b2i, scores);
    select_kernel<<<BATCH, 256, 0, stream>>>(scores, mask);
    apply_kernel<<<8192, 256, 0, stream>>>(keys, values, mask, (float*)d_out);
}

// Round 2
// 560.774 us; speedup vs baseline: 1.4557x; 1.1333x over previous
//
#include <hip/hip_runtime.h>
#include <math.h>

#define H      1024
#define NA     512
#define NI     256
#define SEQ    4096
#define BATCH  4
#define NTOK   (BATCH*SEQ)      // 16384
#define SINKN  4
#define RECENTN 19
#define MIDN   (SEQ - SINKN - RECENTN)   // 4073
#define KSEL   2025
#define CHK    16

#define TT   128                // tokens per tile
#define UT   128                // units per tile
#define KC   32                 // k-chunk staged in LDS
#define PTA  132                // A lds row stride (floats) - pads write conflicts
#define ATT_BLOCKS ((NTOK/TT) * (NA/UT))   // 128*4 = 512
#define IMP_BLOCKS ((NTOK/TT) * (NI/UT))   // 128*2 = 256

// ---------------------------------------------------------------------------
// Kernel 1 (v3): register-blocked GEMM. Each block computes a 128-token x
// 128-unit tile of layer-1 (att over keys/W1a or imp over values/W1i), applies
// relu+b1, dots with the W2 slice, and writes a per-token partial sum to
// part[slot][tok]. 16x16 threads, 8x8 per-thread tile: 4 ds_read_b128 per
// 64 FMAs (vs 5 per 48 in v2 - the measured LDS-instruction bottleneck).
// B is stored quad-swizzled (q ^= q>>3, involution) so the stride-8-float
// read pattern is 2-way bank aliased (free); A transposed reads broadcast
// over tx and are conflict-free. Deterministic summation order throughout.
// ---------------------------------------------------------------------------
__global__ __launch_bounds__(256, 3) void score_gemm_kernel(
    const float* __restrict__ keys, const float* __restrict__ values,
    const float* __restrict__ W1a, const float* __restrict__ b1a,
    const float* __restrict__ W2a,
    const float* __restrict__ W1i, const float* __restrict__ b1i,
    const float* __restrict__ W2i,
    float* __restrict__ part)
{
    __shared__ __align__(16) float smem[KC * PTA + KC * UT];   // 33280 B
    float* A_lds = smem;                 // [KC][PTA] transposed: [h][tok]
    float* B_lds = smem + KC * PTA;      // [KC][UT] quad-swizzled

    const int tid = threadIdx.x;
    const int tx  = tid & 15;            // unit group
    const int ty  = tid >> 4;            // token group
    const int bid = blockIdx.x;

    const bool is_att = bid < ATT_BLOCKS;
    const int  lb     = is_att ? bid : bid - ATT_BLOCKS;
    const int  tile   = is_att ? (lb >> 2) : (lb >> 1);   // consecutive bids share A tile
    const int  pass   = is_att ? (lb & 3)  : (lb & 1);
    const int  slot   = is_att ? pass : 4 + pass;
    const int  tokb   = tile * TT;
    const int  u0     = pass * UT;
    const int  wstride = is_att ? NA : NI;

    const float* Aptr = is_att ? keys : values;
    const float* Wptr = (is_att ? W1a : W1i) + u0;
    const float* b1p  = (is_att ? b1a : b1i) + u0;
    const float* w2p  = (is_att ? W2a : W2i) + u0;

    float acc[8][8];
#pragma unroll
    for (int t = 0; t < 8; ++t)
#pragma unroll
        for (int u = 0; u < 8; ++u) acc[t][u] = 0.f;

    // A staging map: 8 lanes per token -> 128B contiguous segments per token.
    const int at = tid >> 3;             // token 0..31 (+p*32)
    const int aq = tid & 7;              // f4 index within 32-h row
    const float* a_base = Aptr + (size_t)(tokb + at) * H + aq * 4;
    // B staging map: u = (tid&31)*4, row rb = tid>>5 (+p*8)
    const int bu = (tid & 31) * 4;
    const int rb = tid >> 5;
    const float* b_base = Wptr + (size_t)rb * wstride + bu;
    const int bq   = bu >> 2;
    const int bpos = ((bq ^ (bq >> 3)) << 2);            // swizzled write pos
    // B read offsets (constant per thread): quads 2tx, 2tx+1 swizzled
    const int q1 = 2 * tx, q2 = 2 * tx + 1;
    const int boff1 = ((q1 ^ (q1 >> 3)) << 2);
    const int boff2 = ((q2 ^ (q2 >> 3)) << 2);

    for (int h0 = 0; h0 < H; h0 += KC) {
        // issue global loads early (reg dest); overlap the barrier wait
        float4 aR[4], bR[4];
#pragma unroll
        for (int p = 0; p < 4; ++p)
            aR[p] = *(const float4*)(a_base + h0 + (size_t)p * 32 * H);
#pragma unroll
        for (int p = 0; p < 4; ++p)
            bR[p] = *(const float4*)(b_base + (size_t)(h0 + p * 8) * wstride);

        __syncthreads();                 // previous chunk fully consumed
#pragma unroll
        for (int p = 0; p < 4; ++p) {
            A_lds[(aq * 4 + 0) * PTA + at + p * 32] = aR[p].x;
            A_lds[(aq * 4 + 1) * PTA + at + p * 32] = aR[p].y;
            A_lds[(aq * 4 + 2) * PTA + at + p * 32] = aR[p].z;
            A_lds[(aq * 4 + 3) * PTA + at + p * 32] = aR[p].w;
        }
#pragma unroll
        for (int p = 0; p < 4; ++p)
            *(float4*)&B_lds[(rb + p * 8) * UT + bpos] = bR[p];
        __syncthreads();

#pragma unroll 8
        for (int h = 0; h < KC; ++h) {
            float a[8], b[8];
            *(float4*)&a[0] = *(const float4*)&A_lds[h * PTA + ty * 8];
            *(float4*)&a[4] = *(const float4*)&A_lds[h * PTA + ty * 8 + 4];
            *(float4*)&b[0] = *(const float4*)&B_lds[h * UT + boff1];
            *(float4*)&b[4] = *(const float4*)&B_lds[h * UT + boff2];
#pragma unroll
            for (int t = 0; t < 8; ++t)
#pragma unroll
                for (int u = 0; u < 8; ++u)
                    acc[t][u] = fmaf(a[t], b[u], acc[t][u]);
        }
    }

    // ---- epilogue: relu + second-layer slice -> per-token partial ----
    float b1v[8], w2v[8];
    *(float4*)&b1v[0] = *(const float4*)(b1p + tx * 8);
    *(float4*)&b1v[4] = *(const float4*)(b1p + tx * 8 + 4);
    *(float4*)&w2v[0] = *(const float4*)(w2p + tx * 8);
    *(float4*)&w2v[4] = *(const float4*)(w2p + tx * 8 + 4);

    __syncthreads();                     // done with staging LDS
    float* red = smem;                   // [TT][17] padded
#pragma unroll
    for (int t = 0; t < 8; ++t) {
        float s = 0.f;
#pragma unroll
        for (int u = 0; u < 8; ++u)
            s += fmaxf(acc[t][u] + b1v[u], 0.f) * w2v[u];
        red[(ty * 8 + t) * 17 + tx] = s;
    }
    __syncthreads();
    if (tid < TT) {
        float s = 0.f;
        for (int x = 0; x < 16; ++x) s += red[tid * 17 + x];   // fixed order
        part[(size_t)slot * NTOK + tokb + tid] = s;
    }
}

// ---------------------------------------------------------------------------
// block-wide sum (256 threads), result broadcast to all threads
// ---------------------------------------------------------------------------
__device__ __forceinline__ int block_sum(int val, int* red, int tid)
{
#pragma unroll
    for (int off = 32; off > 0; off >>= 1) val += __shfl_down(val, off);
    if ((tid & 63) == 0) red[tid >> 6] = val;
    __syncthreads();
    const int total = red[0] + red[1] + red[2] + red[3];
    __syncthreads();
    return total;
}

// ---------------------------------------------------------------------------
// Kernel 2: combine partials into scores (fixed order) + per-row exact
// top-KSEL via 4-pass byte-radix select with parallel scans -> float mask.
// ---------------------------------------------------------------------------
__global__ __launch_bounds__(256) void select_kernel(
    const float* __restrict__ part, const float* __restrict__ b2a,
    const float* __restrict__ b2i, float* __restrict__ mask)
{
    __shared__ unsigned int ks[MIDN];
    __shared__ int hist[256];
    __shared__ int red[4];
    __shared__ int scan_s[256];
    __shared__ unsigned int sh_pref;
    __shared__ int sh_r;

    const int tid = threadIdx.x;
    const int row = blockIdx.x;
    const float ba  = b2a[0];
    const float bi2 = b2i[0];

    for (int i = tid; i < MIDN; i += 256) {
        const int tok = row * SEQ + SINKN + i;
        float sa = ((part[tok] + part[NTOK + tok]) + part[2 * NTOK + tok]) + part[3 * NTOK + tok];
        float si = part[4 * NTOK + tok] + part[5 * NTOK + tok];
        const float att = 1.f / (1.f + expf(-(sa + ba)));
        const float s = 0.6f * att + 0.4f * (si + bi2);
        unsigned int u = __float_as_uint(s);
        u = (u & 0x80000000u) ? ~u : (u | 0x80000000u);   // order-preserving map
        ks[i] = u;
    }
    if (tid == 0) { sh_pref = 0u; sh_r = KSEL; }
    __syncthreads();

    // byte-radix: after 4 passes sh_pref == KSEL-th largest key value
    for (int b = 3; b >= 0; --b) {
        hist[tid] = 0;
        __syncthreads();
        const unsigned int hi_mask = (b == 3) ? 0u : (0xFFFFFFFFu << ((b + 1) * 8));
        const unsigned int pref = sh_pref;
        for (int i = tid; i < MIDN; i += 256) {
            const unsigned int u = ks[i];
            if ((u & hi_mask) == pref)
                atomicAdd(&hist[(u >> (b * 8)) & 255], 1);
        }
        __syncthreads();

        // inclusive suffix-sum of hist (Hillis-Steele, 8 rounds)
        scan_s[tid] = hist[tid];
        __syncthreads();
#pragma unroll
        for (int off = 1; off < 256; off <<= 1) {
            const int add = (tid + off < 256) ? scan_s[tid + off] : 0;
            __syncthreads();
            scan_s[tid] += add;
            __syncthreads();
        }
        const int r    = sh_r;
        const int sfx  = scan_s[tid];
        const int sfx1 = (tid < 255) ? scan_s[tid + 1] : 0;
        if (sfx >= r && sfx1 < r) {      // unique winner
            sh_r = r - sfx1;
            sh_pref = pref | ((unsigned int)tid << (b * 8));
        }
        __syncthreads();
    }
    const unsigned int v = sh_pref;

    const int st = tid * CHK;
    const int en = (st + CHK < MIDN) ? (st + CHK) : MIDN;

    int cgt = 0, ceq = 0;
    for (int k = st; k < en; ++k) { cgt += (ks[k] > v) ? 1 : 0; ceq += (ks[k] == v) ? 1 : 0; }
    const int total_gt = block_sum(cgt, red, tid);
    const int need = KSEL - total_gt;    // #ties to keep (>=1 by construction)

    // exclusive prefix-sum of tie counts (parallel)
    scan_s[tid] = ceq;
    __syncthreads();
#pragma unroll
    for (int off = 1; off < 256; off <<= 1) {
        const int add = (tid >= off) ? scan_s[tid - off] : 0;
        __syncthreads();
        scan_s[tid] += add;
        __syncthreads();
    }
    int r = scan_s[tid] - ceq;           // exclusive prefix

    float* mr = mask + row * SEQ;
    for (int k = st; k < en; ++k) {
        const unsigned int u = ks[k];
        bool keep = false;
        if (u > v) keep = true;
        else if (u == v) { keep = (r < need); ++r; }
        mr[SINKN + k] = keep ? 1.f : 0.f;
    }
    for (int s = tid; s < SEQ; s += 256) {
        if (s < SINKN || s >= SEQ - RECENTN) mr[s] = 1.f;
    }
}

// ---------------------------------------------------------------------------
// Kernel 3: out = concat(keys*mask, values*mask), float4 grid-stride.
// ---------------------------------------------------------------------------
__global__ __launch_bounds__(256) void apply_kernel(
    const float* __restrict__ keys, const float* __restrict__ values,
    const float* __restrict__ mask, float* __restrict__ out)
{
    const int QT = NTOK * H / 4;          // 4194304 float4 per tensor
    const int stride = gridDim.x * 256;
    for (int i4 = blockIdx.x * 256 + threadIdx.x; i4 < 2 * QT; i4 += stride) {
        const bool isv = (i4 >= QT);
        const int  j4  = isv ? (i4 - QT) : i4;
        const float m  = mask[j4 >> 8];   // 256 float4 per token row
        const float4* src = isv ? (const float4*)values : (const float4*)keys;
        const float4 x = src[j4];
        float4 y; y.x = x.x * m; y.y = x.y * m; y.z = x.z * m; y.w = x.w * m;
        ((float4*)out)[i4] = y;
    }
}

extern "C" void kernel_launch(void* const* d_in, const int* in_sizes, int n_in,
                              void* d_out, int out_size, void* d_ws, size_t ws_size,
                              hipStream_t stream)
{
    const float* keys   = (const float*)d_in[0];
    const float* values = (const float*)d_in[1];
    const float* W1a = (const float*)d_in[2];
    const float* b1a = (const float*)d_in[3];
    const float* W2a = (const float*)d_in[4];
    const float* b2a = (const float*)d_in[5];
    const float* W1i = (const float*)d_in[6];
    const float* b1i = (const float*)d_in[7];
    const float* W2i = (const float*)d_in[8];
    const float* b2i = (const float*)d_in[9];

    float* part = (float*)d_ws;            // 6*NTOK floats (att 0-3, imp 4-5)
    float* mask = part + 6 * NTOK;         // NTOK floats

    score_gemm_kernel<<<ATT_BLOCKS + IMP_BLOCKS, 256, 0, stream>>>(
        keys, values, W1a, b1a, W2a, W1i, b1i, W2i, part);
    select_kernel<<<BATCH, 256, 0, stream>>>(part, b2a, b2i, mask);
    apply_kernel<<<8192, 256, 0, stream>>>(keys, values, mask, (float*)d_out);
}